// Round 12
// baseline (229.423 us; speedup 1.0000x reference)
//
#include <hip/hip_runtime.h>
#include <stdint.h>

#define PP 196            // 14*14
#define BP 6272           // 32*196

typedef _Float16 half_t;
typedef half_t half8v __attribute__((ext_vector_type(8)));
typedef half_t half4v __attribute__((ext_vector_type(4)));
typedef half_t half2v __attribute__((ext_vector_type(2)));

// ===========================================================================
// R12 = R11 + single-barrier double-buffered accum (T14 within-iteration
// async split). R11 counters: accum 43.5us vs ~39us LDS floor (gathers 31 +
// writes 8); the 2-barrier/chunk loop drains the pipe 32x/block. R12: one
// barrier/chunk, loads for ch+1 issued BEFORE the gathers of ch (gather
// block ~300+cy hides global latency), staged regs live only within one
// iteration (NOT the R2 cross-barrier spill pattern).
// Measured harness floor (R11 top-5): 43.2us fillBufferAligned = 256MiB
// workspace re-poison per iteration + out-memset + reset dispatches ~100us
// of the window is harness-side; kernel-side floor is what we optimize.
// ===========================================================================

// ---------------------------------------------------------------------------
// assign kernels (layers 1,2): nearest-centroid 4-bit indices, packed 8/u32.
// f32 SCREEN + f64 FIXUP: screen tracks best/second-best; iff any lane's gap
// < TAU the wave re-runs that codebook with exact f64 arithmetic.
// ---------------------------------------------------------------------------

template <typename T>
__global__ __launch_bounds__(256) void assign_1x1(
    const T* __restrict__ in, const float* __restrict__ cents,
    uint32_t* __restrict__ idxp, int nchan) {
  __shared__ float  sf[8][16][4];     // screen rows (16 B, one b128)
  __shared__ double sd[8][16][6];     // [c2, c0..c3, pad]: 48 B rows
  const int chunk = blockIdx.y;
  const int t = threadIdx.x;
  for (int i = t; i < 512; i += 256) {
    float c = cents[(size_t)chunk * 512 + i];
    int cb = i >> 6, r = i & 63;      // r = k*4 + d
    sf[cb][r >> 2][r & 3] = c;
    sd[cb][r >> 2][1 + (r & 3)] = (double)c;
  }
  __syncthreads();
  if (t < 128) {
    int cb = t >> 4, k = t & 15;
    double s = 0.0;
#pragma unroll
    for (int d = 0; d < 4; d++) { double c = sd[cb][k][1 + d]; s += c * c; }
    sd[cb][k][0] = s;
  }
  __syncthreads();
  const int p = blockIdx.x * 256 + t;
  if (p >= BP) return;
  const unsigned b = (unsigned)p / 196u;
  const unsigned pr = (unsigned)p - b * 196u;
  const T* xb = in + ((size_t)b * nchan + chunk * 32) * PP + pr;
  T xr[32];
#pragma unroll
  for (int i = 0; i < 32; i++) xr[i] = xb[(size_t)i * PP];
  float xs2[32];
#pragma unroll
  for (int i = 0; i < 32; i++) xs2[i] = 2.f * (float)xr[i];
  uint32_t word = 0;
#pragma unroll 1
  for (int cb = 0; cb < 8; cb++) {
    float best = 1e30f, sec = 1e30f; int bi = 0;
#pragma unroll
    for (int k = 0; k < 16; k++) {
      const float4 c = *(const float4*)&sf[cb][k][0];
      float dist = c.x * (c.x - xs2[cb * 4 + 0]);
      dist = fmaf(c.y, c.y - xs2[cb * 4 + 1], dist);
      dist = fmaf(c.z, c.z - xs2[cb * 4 + 2], dist);
      dist = fmaf(c.w, c.w - xs2[cb * 4 + 3], dist);
      if (dist < best) { sec = best; best = dist; bi = k; }
      else sec = fminf(sec, dist);
    }
    if (__any(sec - best < 2e-4f)) {
      double xv[4];
#pragma unroll
      for (int d = 0; d < 4; d++) xv[d] = (double)xr[cb * 4 + d];
      double bb = 1e300; int bi64 = 0;
#pragma unroll
      for (int k = 0; k < 16; k++) {
        double dot = 0.0;
#pragma unroll
        for (int d = 0; d < 4; d++) dot = fma(xv[d], sd[cb][k][1 + d], dot);
        double dist = sd[cb][k][0] - 2.0 * dot;
        if (dist < bb) { bb = dist; bi64 = k; }   // strict <: first-min
      }
      bi = bi64;
    }
    word |= (uint32_t)bi << (4 * cb);
  }
  idxp[(size_t)chunk * BP + p] = word;
}

// ---------------------------------------------------------------------------
// assign_3x3 (R8-verified): input is the layer-1 output in F32 (the
// reference's own intermediate dtype). Screen reads the 9 f32 values; fixup
// upconverts those SAME registers to f64 (no reload). Neighborhood hoisted.
// ---------------------------------------------------------------------------
__global__ __launch_bounds__(256) void assign_3x3(
    const float* __restrict__ in, const float* __restrict__ cents,
    uint32_t* __restrict__ idxp) {
  __shared__ float  sf[8][16][12];    // [c2f, c0..c8, pad, pad]: 48 B rows
  __shared__ double sd[8][16][10];    // [c2, c0..c8]: 80 B rows
  const int chunk = blockIdx.y;
  const int c0g = chunk * 8;
  const int t = threadIdx.x;
  for (int i = t; i < 1152; i += 256) {
    int cb = i / 144, r = i - cb * 144;
    int k = r / 9, d = r - k * 9;
    float c = cents[(size_t)(c0g + cb) * 144 + k * 9 + d];
    sf[cb][k][1 + d] = c;
    sd[cb][k][1 + d] = (double)c;
  }
  __syncthreads();
  if (t < 128) {
    int cb = t >> 4, k = t & 15;
    double s = 0.0;
    float s32 = 0.f;
#pragma unroll
    for (int d = 0; d < 9; d++) {
      double c = sd[cb][k][1 + d]; s += c * c;
      float cf = sf[cb][k][1 + d]; s32 += cf * cf;
    }
    sd[cb][k][0] = s;
    sf[cb][k][0] = s32;
  }
  __syncthreads();
  const int p = blockIdx.x * 256 + t;
  if (p >= BP) return;
  const unsigned b = (unsigned)p / 196u;
  const unsigned pr = (unsigned)p - b * 196u;
  const int oh = pr / 14, ow = pr - oh * 14;
  // hoisted 3x3 neighborhood (cb-invariant)
  int  noff[9]; bool nok[9];
#pragma unroll
  for (int r = 0; r < 3; r++) {
#pragma unroll
    for (int cc = 0; cc < 3; cc++) {
      int hh = oh + r - 1, ww = ow + cc - 1;
      nok[r * 3 + cc] = (hh >= 0) & (hh < 14) & (ww >= 0) & (ww < 14);
      noff[r * 3 + cc] = hh * 14 + ww;
    }
  }
  uint32_t word = 0;
#pragma unroll 1
  for (int cb = 0; cb < 8; cb++) {
    const float* basef = in + ((size_t)b * 256 + (c0g + cb)) * PP;
    float v32[9];
#pragma unroll
    for (int i = 0; i < 9; i++) v32[i] = nok[i] ? basef[noff[i]] : 0.f;
    float best = 1e30f, sec = 1e30f; int bi = 0;
#pragma unroll
    for (int k = 0; k < 16; k++) {
      const float4 cA = *(const float4*)&sf[cb][k][0];  // c2f,c0,c1,c2
      const float4 cB = *(const float4*)&sf[cb][k][4];  // c3..c6
      const float4 cC = *(const float4*)&sf[cb][k][8];  // c7,c8,pad,pad
      float dot = v32[0] * cA.y;
      dot = fmaf(v32[1], cA.z, dot);
      dot = fmaf(v32[2], cA.w, dot);
      dot = fmaf(v32[3], cB.x, dot);
      dot = fmaf(v32[4], cB.y, dot);
      dot = fmaf(v32[5], cB.z, dot);
      dot = fmaf(v32[6], cB.w, dot);
      dot = fmaf(v32[7], cC.x, dot);
      dot = fmaf(v32[8], cC.y, dot);
      float dist = fmaf(-2.f, dot, cA.x);
      if (dist < best) { sec = best; best = dist; bi = k; }
      else sec = fminf(sec, dist);
    }
    if (__any(sec - best < 4e-4f)) {
      double bb = 1e300; int bi64 = 0;
#pragma unroll
      for (int k = 0; k < 16; k++) {
        double dot = 0.0;
#pragma unroll
        for (int d = 0; d < 9; d++)
          dot = fma((double)v32[d], sd[cb][k][1 + d], dot);
        double dist = sd[cb][k][0] - 2.0 * dot;
        if (dist < bb) { bb = dist; bi64 = k; }
      }
      bi = bi64;
    }
    word |= (uint32_t)bi << (4 * cb);
  }
  idxp[(size_t)chunk * BP + p] = word;
}

// ---------------------------------------------------------------------------
// accum v11 (f64-grade): R6/R8's proven per-chunk code (XOR swizzle,
// coalesced staging, quad-f32 accumulation, conflicts 25K) restructured to
// SINGLE barrier per chunk with a 2x16KB LDS double buffer:
//   iter ch: issue loads for ch+1 -> gather ch from buf[ch&1] (hides the
//   ~300cy load latency) -> write regs to buf[(ch+1)&1] -> barrier.
// WAR safety: writes at iter ch target the buffer last gathered at iter
// ch-1 (separated by that iteration's barrier); gathers at iter ch read the
// buffer written at iter ch-1 (same barrier). Staged regs (v0..v3, nw0/nw1)
// live within ONE iteration only -- not the R2 cross-barrier spill pattern.
// ---------------------------------------------------------------------------
template <int NCB, int NOUT, bool RELU, bool FUSE3, typename OutT>
__global__ __launch_bounds__(256) void accum_f64(
    const float* __restrict__ lut, const uint32_t* __restrict__ idxp,
    const float* __restrict__ scale, const float* __restrict__ bias,
    const float* __restrict__ c3cent, uint8_t* __restrict__ i3b,
    OutT* __restrict__ out) {
  __shared__ float s_lut[2 * 4096];   // 32 KB: 2 x (16 cb x 16 k x 16 out)
  __shared__ float  c3f[4][16][4];
  __shared__ float  c3c2f[4][16];
  __shared__ double c3d[4][16][4];
  __shared__ double c3c2d[4][16];
  const int t = threadIdx.x;
  const int lane = t & 63;
  const int q = t >> 6;                 // channel quad 0..3 (wave id)
  const int p = blockIdx.x * 64 + lane; // 98*64 = 6272 = BP exactly
  const int o_base = blockIdx.y * 16;
  if (FUSE3 && t < 64) {
    int cb_l = t >> 4, k = t & 15;
    const float4 cf = *(const float4*)(c3cent + ((size_t)(blockIdx.y * 4 + cb_l)) * 64 + k * 4);
    c3f[cb_l][k][0] = cf.x; c3f[cb_l][k][1] = cf.y;
    c3f[cb_l][k][2] = cf.z; c3f[cb_l][k][3] = cf.w;
    double d0 = (double)cf.x, d1 = (double)cf.y, d2 = (double)cf.z, d3 = (double)cf.w;
    c3d[cb_l][k][0] = d0; c3d[cb_l][k][1] = d1;
    c3d[cb_l][k][2] = d2; c3d[cb_l][k][3] = d3;
    double s = 0.0; s += d0 * d0; s += d1 * d1; s += d2 * d2; s += d3 * d3;
    c3c2d[cb_l][k] = s;
    float s32 = 0.f; s32 += cf.x * cf.x; s32 += cf.y * cf.y;
    s32 += cf.z * cf.z; s32 += cf.w * cf.w;
    c3c2f[cb_l][k] = s32;
  }
  // staging ownership (coalesced source): thread t owns cb=(t>>6)+4j,
  // q_s = t&3, k = (t>>2)&15; 4 consecutive lanes = 64B contiguous of one row.
  const float* src = lut + ((size_t)(t >> 6) * 16 + ((t >> 2) & 15)) * NOUT
                         + o_base + (t & 3) * 4;
  const int kk = (t >> 2) & 15, qs = t & 3;
  const int sslot = (t >> 6) * 64 + qs * 16 + (kk ^ (2 * qs));
  const int q2 = q * 2;               // wave-uniform gather swizzle term
  double a0 = 0, a1 = 0, a2 = 0, a3 = 0;
  constexpr int NCHUNK = NCB / 16;
  // prologue: stage chunk 0 -> buf 0, load its idx words
  {
#pragma unroll
    for (int j = 0; j < 4; j++) {
      float4 v = *(const float4*)(src + (size_t)(64 * j) * NOUT);
      *(float4*)(s_lut + (sslot + 256 * j) * 4) = v;
    }
  }
  uint32_t w0 = idxp[p];
  uint32_t w1 = idxp[(size_t)BP + p];
  __syncthreads();   // chunk 0 + c3 tables published
#pragma unroll 1
  for (int ch = 0; ch < NCHUNK; ch++) {
    const bool more = (ch + 1 < NCHUNK);
    // issue next chunk's loads FIRST (latency hidden under the gathers)
    float4 v0, v1, v2, v3;
    uint32_t nw0, nw1;
    if (more) {
      const float* g = src + (size_t)((ch + 1) * 256) * NOUT;
      v0 = *(const float4*)(g);
      v1 = *(const float4*)(g + (size_t)64 * NOUT);
      v2 = *(const float4*)(g + (size_t)128 * NOUT);
      v3 = *(const float4*)(g + (size_t)192 * NOUT);
      nw0 = idxp[(size_t)(ch * 2 + 2) * BP + p];
      nw1 = idxp[(size_t)(ch * 2 + 3) * BP + p];
    }
    // gather current chunk
    const float* buf = s_lut + (ch & 1) * 4096 + q * 64;
#pragma unroll
    for (int jq = 0; jq < 4; jq++) {   // cb quad (4jq .. 4jq+3)
      const int cbb = 4 * jq * 256;
      uint32_t w = (jq < 2) ? w0 : w1;
      int sh = (jq & 1) * 16;
      int i0 = (int)((w >> sh) & 15u);
      int i1 = (int)((w >> (sh + 4)) & 15u);
      int i2 = (int)((w >> (sh + 8)) & 15u);
      int i3 = (int)((w >> (sh + 12)) & 15u);
      const float4 va = *(const float4*)(buf + cbb       + (i0 ^ q2) * 4);
      const float4 vb = *(const float4*)(buf + cbb + 256 + (i1 ^ q2) * 4);
      const float4 vc = *(const float4*)(buf + cbb + 512 + (i2 ^ q2) * 4);
      const float4 vd = *(const float4*)(buf + cbb + 768 + (i3 ^ q2) * 4);
      float s0 = (va.x + vb.x) + (vc.x + vd.x);
      float s1 = (va.y + vb.y) + (vc.y + vd.y);
      float s2 = (va.z + vb.z) + (vc.z + vd.z);
      float s3 = (va.w + vb.w) + (vc.w + vd.w);
      a0 += (double)s0; a1 += (double)s1; a2 += (double)s2; a3 += (double)s3;
    }
    // publish next chunk into the other buffer, then the single barrier
    if (more) {
      float* d = s_lut + ((ch + 1) & 1) * 4096;
      *(float4*)(d + (sslot      ) * 4) = v0;
      *(float4*)(d + (sslot + 256) * 4) = v1;
      *(float4*)(d + (sslot + 512) * 4) = v2;
      *(float4*)(d + (sslot + 768) * 4) = v3;
      w0 = nw0; w1 = nw1;
    }
    __syncthreads();
  }
  const unsigned b = (unsigned)p / 196u;
  const unsigned pr = (unsigned)p - b * 196u;
  const int o = o_base + q * 4;
  const float4 sc = *(const float4*)(scale + o);
  const float4 bs = *(const float4*)(bias + o);
  double r0 = a0 * (double)sc.x + (double)bs.x;
  double r1 = a1 * (double)sc.y + (double)bs.y;
  double r2 = a2 * (double)sc.z + (double)bs.z;
  double r3 = a3 * (double)sc.w + (double)bs.w;
  if (RELU) {
    r0 = fmax(r0, 0.0); r1 = fmax(r1, 0.0);
    r2 = fmax(r2, 0.0); r3 = fmax(r3, 0.0);
  }
  if (FUSE3) {
    // layer-3 assignment for codebook cb3 = blockIdx.y*4 + q (this thread's 4 ch)
    const int cb_l = q;
    float x0 = (float)r0, x1 = (float)r1, x2 = (float)r2, x3 = (float)r3;
    float best = 1e30f, sec = 1e30f; int bi = 0;
#pragma unroll
    for (int k = 0; k < 16; k++) {
      const float4 c = *(const float4*)&c3f[cb_l][k][0];
      float dot = x0 * c.x;
      dot = fmaf(x1, c.y, dot);
      dot = fmaf(x2, c.z, dot);
      dot = fmaf(x3, c.w, dot);
      float dist = fmaf(-2.f, dot, c3c2f[cb_l][k]);
      if (dist < best) { sec = best; best = dist; bi = k; }
      else sec = fminf(sec, dist);
    }
    if (__any(sec - best < 1e-3f)) {
      double bb = 1e300; int bi64 = 0;
#pragma unroll
      for (int k = 0; k < 16; k++) {
        double dot = 0.0;
        dot = fma(r0, c3d[cb_l][k][0], dot);
        dot = fma(r1, c3d[cb_l][k][1], dot);
        dot = fma(r2, c3d[cb_l][k][2], dot);
        dot = fma(r3, c3d[cb_l][k][3], dot);
        double dist = c3c2d[cb_l][k] - 2.0 * dot;
        if (dist < bb) { bb = dist; bi64 = k; }   // strict <: first-min
      }
      bi = bi64;
    }
    // transposed layout: i3b[chunk16][p][16]  (chunk16 = cb3>>4, byte = cb3&15)
    i3b[((size_t)(blockIdx.y >> 2) * BP + p) * 16 + (blockIdx.y & 3) * 4 + q] =
        (uint8_t)bi;
  } else {
    OutT* op = out + ((size_t)b * NOUT + o) * PP + pr;
    op[0 * PP] = (OutT)r0; op[1 * PP] = (OutT)r1;
    op[2 * PP] = (OutT)r2; op[3 * PP] = (OutT)r3;
  }
}

// ---------------------------------------------------------------------------
// accum3 v3 (R11-verified): 256 positions per block (grid 25x64) -- each
// staged chunk serves TWO position-groups, halving LUT->LDS staging traffic.
// Tail block (x=24) covers p 6144..6271 in group A; group B fully guarded.
// Staging: 4 lanes x float4 per LUT row; ds_write_b64 at row*80 + c*8 ->
// conflict-free. Rows 40 halfs: gather quad (5*idx+h)%8 bijective -> 2-way
// = free. Index reads: lane-contiguous dwordx4 from transposed i3b.
// ---------------------------------------------------------------------------
__global__ __launch_bounds__(256) void accum3_f16(
    const float* __restrict__ lut, const uint8_t* __restrict__ i3b,
    const float* __restrict__ scale, const float* __restrict__ bias,
    const float* __restrict__ res, float* __restrict__ out) {
  __shared__ half_t s16[16 * 640];   // 20 KB
  const int t = threadIdx.x;
  const int lane = t & 63;
  const int wave = t >> 6;           // 0..3
  const int h = wave & 1;            // channel half (8 f16 ch)
  const int pg = wave >> 1;          // 0..1
  const int pA = blockIdx.x * 256 + pg * 64 + lane;   // always < BP
  const int pB = pA + 128;                            // may exceed BP (x=24)
  const bool okB = (pB < BP);
  const int pBc = okB ? pB : (BP - 1);                // clamped for loads
  const int o_base = blockIdx.y * 16;
  const int rs = t >> 2, cg = t & 3;
  const size_t cs = (size_t)16 * 16 * 1024;     // 16 cb per chunk (f32 elems)
  constexpr int NCHUNK = 4;
  float accA[8], accB[8];
#pragma unroll
  for (int i = 0; i < 8; i++) { accA[i] = 0.f; accB[i] = 0.f; }
  for (int ch = 0; ch < NCHUNK; ch++) {
    __syncthreads();
    const uint4 iwA = *(const uint4*)(i3b + ((size_t)ch * BP + pA) * 16);
    const uint4 iwB = *(const uint4*)(i3b + ((size_t)ch * BP + pBc) * 16);
    {
#pragma unroll
      for (int j = 0; j < 4; j++) {
        const int r = rs + 64 * j;
        const float4 v = *(const float4*)(lut + (size_t)ch * cs +
                                          (size_t)r * 1024 + o_base + cg * 4);
        half4v hv;
        hv[0] = (half_t)v.x; hv[1] = (half_t)v.y;
        hv[2] = (half_t)v.z; hv[3] = (half_t)v.w;
        *(half4v*)(s16 + (r >> 4) * 640 + (r & 15) * 40 + cg * 4) = hv;
      }
    }
    __syncthreads();
#pragma unroll
    for (int grp = 0; grp < 2; grp++) {   // 8 cb per f32 flush
      // ---- position group A ----
      {
        uint32_t wa = grp ? iwA.z : iwA.x;
        uint32_t wb = grp ? iwA.w : iwA.y;
        half2v p0 = 0, p1 = 0, p2 = 0, p3 = 0;
#pragma unroll
        for (int j = 0; j < 8; j++) {
          uint32_t w = (j < 4) ? wa : wb;
          int idx = (int)((w >> ((j & 3) * 8)) & 15u);
          int cb_l = grp * 8 + j;
          const half8v v = *(const half8v*)(s16 + cb_l * 640 + idx * 40 + h * 8);
          const half2v* vp = (const half2v*)&v;
          p0 += vp[0]; p1 += vp[1]; p2 += vp[2]; p3 += vp[3];
        }
        accA[0] += (float)p0[0]; accA[1] += (float)p0[1];
        accA[2] += (float)p1[0]; accA[3] += (float)p1[1];
        accA[4] += (float)p2[0]; accA[5] += (float)p2[1];
        accA[6] += (float)p3[0]; accA[7] += (float)p3[1];
      }
      // ---- position group B ----
      {
        uint32_t wa = grp ? iwB.z : iwB.x;
        uint32_t wb = grp ? iwB.w : iwB.y;
        half2v p0 = 0, p1 = 0, p2 = 0, p3 = 0;
#pragma unroll
        for (int j = 0; j < 8; j++) {
          uint32_t w = (j < 4) ? wa : wb;
          int idx = (int)((w >> ((j & 3) * 8)) & 15u);
          int cb_l = grp * 8 + j;
          const half8v v = *(const half8v*)(s16 + cb_l * 640 + idx * 40 + h * 8);
          const half2v* vp = (const half2v*)&v;
          p0 += vp[0]; p1 += vp[1]; p2 += vp[2]; p3 += vp[3];
        }
        accB[0] += (float)p0[0]; accB[1] += (float)p0[1];
        accB[2] += (float)p1[0]; accB[3] += (float)p1[1];
        accB[4] += (float)p2[0]; accB[5] += (float)p2[1];
        accB[6] += (float)p3[0]; accB[7] += (float)p3[1];
      }
    }
  }
  const int o = o_base + h * 8;
  {
    const unsigned b = (unsigned)pA / 196u;
    const unsigned pr = (unsigned)pA - b * 196u;
    const float* rp = res + ((size_t)b * 1024 + o) * PP + pr;
    float* op = out + ((size_t)b * 1024 + o) * PP + pr;
#pragma unroll
    for (int i = 0; i < 8; i++) {
      float v = accA[i] * scale[o + i] + bias[o + i] + rp[(size_t)i * PP];
      op[(size_t)i * PP] = fmaxf(v, 0.f);
    }
  }
  if (okB) {
    const unsigned b = (unsigned)pB / 196u;
    const unsigned pr = (unsigned)pB - b * 196u;
    const float* rp = res + ((size_t)b * 1024 + o) * PP + pr;
    float* op = out + ((size_t)b * 1024 + o) * PP + pr;
#pragma unroll
    for (int i = 0; i < 8; i++) {
      float v = accB[i] * scale[o + i] + bias[o + i] + rp[(size_t)i * PP];
      op[(size_t)i * PP] = fmaxf(v, 0.f);
    }
  }
}

// ---------------------------------------------------------------------------

extern "C" void kernel_launch(void* const* d_in, const int* in_sizes, int n_in,
                              void* d_out, int out_size, void* d_ws, size_t ws_size,
                              hipStream_t stream) {
  const float* x   = (const float*)d_in[0];   // [32,1024,14,14]
  const float* c1c = (const float*)d_in[1];
  const float* c1l = (const float*)d_in[2];
  const float* c1s = (const float*)d_in[3];
  const float* c1b = (const float*)d_in[4];
  const float* c2c = (const float*)d_in[5];
  const float* c2l = (const float*)d_in[6];
  const float* c2s = (const float*)d_in[7];
  const float* c2b = (const float*)d_in[8];
  const float* c3c = (const float*)d_in[9];
  const float* c3l = (const float*)d_in[10];  // [64,16,1024]
  const float* c3s = (const float*)d_in[11];
  const float* c3b = (const float*)d_in[12];

  const size_t sz_i1  = (size_t)32 * BP * 4;      // 802,816 B
  const size_t sz_i2  = (size_t)32 * BP * 4;
  const size_t sz_i3b = (size_t)BP * 64;          // 401,408 B (byte indices)
  const size_t sz_o32 = (size_t)BP * 256 * 4;     // 6.42 MB (f32 layer-1 out)

  char* w = (char*)d_ws;
  uint32_t* i1 = (uint32_t*)w; w += sz_i1;
  uint32_t* i2 = (uint32_t*)w; w += sz_i2;
  uint8_t* i3b = (uint8_t*)w;  w += sz_i3b;
  float* out1;
  if (ws_size >= (size_t)(w - (char*)d_ws) + sz_o32) {
    out1 = (float*)w;
  } else {
    // d_out (25.69 MB f32) holds out1 (6.42 MB f32) in its first quarter;
    // accum3 (final) reads only i3b/x/c3l, then overwrites all of d_out.
    out1 = (float*)d_out;
  }

  const dim3 blkA(256), blkC(256);
  // layer 1: 1x1, 256 codebooks (dsub=4) over 1024 input channels
  assign_1x1<float><<<dim3(25, 32), blkA, 0, stream>>>(x, c1c, i1, 1024);
  accum_f64<256, 256, true, false, float><<<dim3(98, 16), blkC, 0, stream>>>(
      c1l, i1, c1s, c1b, nullptr, nullptr, out1);
  // layer 2: 3x3, 256 codebooks (dsub=9); epilogue fuses the layer-3 assign
  assign_3x3<<<dim3(25, 32), blkA, 0, stream>>>(out1, c2c, i2);
  accum_f64<256, 256, true, true, float><<<dim3(98, 16), blkC, 0, stream>>>(
      c2l, i2, c2s, c2b, c3c, i3b, nullptr);
  // layer 3: 64 codebooks over 256 channels; fused residual + relu
  accum3_f16<<<dim3(25, 64), blkC, 0, stream>>>(
      c3l, i3b, c3s, c3b, x, (float*)d_out);
}

// Round 13
// 220.246 us; speedup vs baseline: 1.0417x; 1.0417x over previous
//
#include <hip/hip_runtime.h>
#include <stdint.h>

#define PP 196            // 14*14
#define BP 6272           // 32*196

typedef _Float16 half_t;
typedef half_t half8v __attribute__((ext_vector_type(8)));
typedef half_t half4v __attribute__((ext_vector_type(4)));
typedef half_t half2v __attribute__((ext_vector_type(2)));

// ===========================================================================
// R13 = exact R11 restore (session best: 225.1us, absmax 0.03125).
// R12 post-mortem: single-barrier double-buffer raised LDS 20.5->36.9KB,
// occupancy 43->31%, accum 43.5->50.3us -- THIRD occupancy-vs-per-block
// tradeoff loss (R7 2-pos: occ 42->18%; R12 dbuf: 43->31%). The accum's
// 2-barrier/16KB/36-VGPR config at 3.4 blocks/CU hides stalls via
// inter-block wave overlap; residency is the binding resource.
// Floor accounting (R11 counters): accum 2x43.5us (~11% above the 39us
// LDS-issue floor; unreachable without occupancy loss or f16 LUTs, which
// are precision-barred by downstream argmins); harness fill/memset ~100us
// (fillBufferAligned 43.2us @ 6.2TB/s, immovable -- R10 fusion proved it);
// assigns+accum3 ~35-40us VALU/L2-bound.
// ===========================================================================

// ---------------------------------------------------------------------------
// assign kernels (layers 1,2): nearest-centroid 4-bit indices, packed 8/u32.
// f32 SCREEN + f64 FIXUP: screen tracks best/second-best; iff any lane's gap
// < TAU the wave re-runs that codebook with exact f64 arithmetic.
// ---------------------------------------------------------------------------

template <typename T>
__global__ __launch_bounds__(256) void assign_1x1(
    const T* __restrict__ in, const float* __restrict__ cents,
    uint32_t* __restrict__ idxp, int nchan) {
  __shared__ float  sf[8][16][4];     // screen rows (16 B, one b128)
  __shared__ double sd[8][16][6];     // [c2, c0..c3, pad]: 48 B rows
  const int chunk = blockIdx.y;
  const int t = threadIdx.x;
  for (int i = t; i < 512; i += 256) {
    float c = cents[(size_t)chunk * 512 + i];
    int cb = i >> 6, r = i & 63;      // r = k*4 + d
    sf[cb][r >> 2][r & 3] = c;
    sd[cb][r >> 2][1 + (r & 3)] = (double)c;
  }
  __syncthreads();
  if (t < 128) {
    int cb = t >> 4, k = t & 15;
    double s = 0.0;
#pragma unroll
    for (int d = 0; d < 4; d++) { double c = sd[cb][k][1 + d]; s += c * c; }
    sd[cb][k][0] = s;
  }
  __syncthreads();
  const int p = blockIdx.x * 256 + t;
  if (p >= BP) return;
  const unsigned b = (unsigned)p / 196u;
  const unsigned pr = (unsigned)p - b * 196u;
  const T* xb = in + ((size_t)b * nchan + chunk * 32) * PP + pr;
  T xr[32];
#pragma unroll
  for (int i = 0; i < 32; i++) xr[i] = xb[(size_t)i * PP];
  float xs2[32];
#pragma unroll
  for (int i = 0; i < 32; i++) xs2[i] = 2.f * (float)xr[i];
  uint32_t word = 0;
#pragma unroll 1
  for (int cb = 0; cb < 8; cb++) {
    float best = 1e30f, sec = 1e30f; int bi = 0;
#pragma unroll
    for (int k = 0; k < 16; k++) {
      const float4 c = *(const float4*)&sf[cb][k][0];
      float dist = c.x * (c.x - xs2[cb * 4 + 0]);
      dist = fmaf(c.y, c.y - xs2[cb * 4 + 1], dist);
      dist = fmaf(c.z, c.z - xs2[cb * 4 + 2], dist);
      dist = fmaf(c.w, c.w - xs2[cb * 4 + 3], dist);
      if (dist < best) { sec = best; best = dist; bi = k; }
      else sec = fminf(sec, dist);
    }
    if (__any(sec - best < 2e-4f)) {
      double xv[4];
#pragma unroll
      for (int d = 0; d < 4; d++) xv[d] = (double)xr[cb * 4 + d];
      double bb = 1e300; int bi64 = 0;
#pragma unroll
      for (int k = 0; k < 16; k++) {
        double dot = 0.0;
#pragma unroll
        for (int d = 0; d < 4; d++) dot = fma(xv[d], sd[cb][k][1 + d], dot);
        double dist = sd[cb][k][0] - 2.0 * dot;
        if (dist < bb) { bb = dist; bi64 = k; }   // strict <: first-min
      }
      bi = bi64;
    }
    word |= (uint32_t)bi << (4 * cb);
  }
  idxp[(size_t)chunk * BP + p] = word;
}

// ---------------------------------------------------------------------------
// assign_3x3 (R8-verified): input is the layer-1 output in F32 (the
// reference's own intermediate dtype). Screen reads the 9 f32 values; fixup
// upconverts those SAME registers to f64 (no reload). Neighborhood hoisted.
// ---------------------------------------------------------------------------
__global__ __launch_bounds__(256) void assign_3x3(
    const float* __restrict__ in, const float* __restrict__ cents,
    uint32_t* __restrict__ idxp) {
  __shared__ float  sf[8][16][12];    // [c2f, c0..c8, pad, pad]: 48 B rows
  __shared__ double sd[8][16][10];    // [c2, c0..c8]: 80 B rows
  const int chunk = blockIdx.y;
  const int c0g = chunk * 8;
  const int t = threadIdx.x;
  for (int i = t; i < 1152; i += 256) {
    int cb = i / 144, r = i - cb * 144;
    int k = r / 9, d = r - k * 9;
    float c = cents[(size_t)(c0g + cb) * 144 + k * 9 + d];
    sf[cb][k][1 + d] = c;
    sd[cb][k][1 + d] = (double)c;
  }
  __syncthreads();
  if (t < 128) {
    int cb = t >> 4, k = t & 15;
    double s = 0.0;
    float s32 = 0.f;
#pragma unroll
    for (int d = 0; d < 9; d++) {
      double c = sd[cb][k][1 + d]; s += c * c;
      float cf = sf[cb][k][1 + d]; s32 += cf * cf;
    }
    sd[cb][k][0] = s;
    sf[cb][k][0] = s32;
  }
  __syncthreads();
  const int p = blockIdx.x * 256 + t;
  if (p >= BP) return;
  const unsigned b = (unsigned)p / 196u;
  const unsigned pr = (unsigned)p - b * 196u;
  const int oh = pr / 14, ow = pr - oh * 14;
  // hoisted 3x3 neighborhood (cb-invariant)
  int  noff[9]; bool nok[9];
#pragma unroll
  for (int r = 0; r < 3; r++) {
#pragma unroll
    for (int cc = 0; cc < 3; cc++) {
      int hh = oh + r - 1, ww = ow + cc - 1;
      nok[r * 3 + cc] = (hh >= 0) & (hh < 14) & (ww >= 0) & (ww < 14);
      noff[r * 3 + cc] = hh * 14 + ww;
    }
  }
  uint32_t word = 0;
#pragma unroll 1
  for (int cb = 0; cb < 8; cb++) {
    const float* basef = in + ((size_t)b * 256 + (c0g + cb)) * PP;
    float v32[9];
#pragma unroll
    for (int i = 0; i < 9; i++) v32[i] = nok[i] ? basef[noff[i]] : 0.f;
    float best = 1e30f, sec = 1e30f; int bi = 0;
#pragma unroll
    for (int k = 0; k < 16; k++) {
      const float4 cA = *(const float4*)&sf[cb][k][0];  // c2f,c0,c1,c2
      const float4 cB = *(const float4*)&sf[cb][k][4];  // c3..c6
      const float4 cC = *(const float4*)&sf[cb][k][8];  // c7,c8,pad,pad
      float dot = v32[0] * cA.y;
      dot = fmaf(v32[1], cA.z, dot);
      dot = fmaf(v32[2], cA.w, dot);
      dot = fmaf(v32[3], cB.x, dot);
      dot = fmaf(v32[4], cB.y, dot);
      dot = fmaf(v32[5], cB.z, dot);
      dot = fmaf(v32[6], cB.w, dot);
      dot = fmaf(v32[7], cC.x, dot);
      dot = fmaf(v32[8], cC.y, dot);
      float dist = fmaf(-2.f, dot, cA.x);
      if (dist < best) { sec = best; best = dist; bi = k; }
      else sec = fminf(sec, dist);
    }
    if (__any(sec - best < 4e-4f)) {
      double bb = 1e300; int bi64 = 0;
#pragma unroll
      for (int k = 0; k < 16; k++) {
        double dot = 0.0;
#pragma unroll
        for (int d = 0; d < 9; d++)
          dot = fma((double)v32[d], sd[cb][k][1 + d], dot);
        double dist = sd[cb][k][0] - 2.0 * dot;
        if (dist < bb) { bb = dist; bi64 = k; }
      }
      bi = bi64;
    }
    word |= (uint32_t)bi << (4 * cb);
  }
  idxp[(size_t)chunk * BP + p] = word;
}

// ---------------------------------------------------------------------------
// accum (f64-grade, R6/R8-verified 42.9us config): 1 pos/thread, grid 98x16,
// XOR swizzle slot = cb*64 + qs*16 + (k ^ 2qs), coalesced staging, quad-f32
// accumulation, conflicts 25K. Layer-1 output F32.
// FUSE3 (layer 2): epilogue computes the layer-3 assignment in-register;
// i3b transposed [chunk16][p][16B] for accum3's lane-contiguous index read.
// ---------------------------------------------------------------------------
template <int NCB, int NOUT, bool RELU, bool FUSE3, typename OutT>
__global__ __launch_bounds__(256) void accum_f64(
    const float* __restrict__ lut, const uint32_t* __restrict__ idxp,
    const float* __restrict__ scale, const float* __restrict__ bias,
    const float* __restrict__ c3cent, uint8_t* __restrict__ i3b,
    OutT* __restrict__ out) {
  __shared__ float s_lut[4096];       // 16 KB: 16 cb x 16 k x 16 out
  __shared__ float  c3f[4][16][4];
  __shared__ float  c3c2f[4][16];
  __shared__ double c3d[4][16][4];
  __shared__ double c3c2d[4][16];
  const int t = threadIdx.x;
  const int lane = t & 63;
  const int q = t >> 6;                 // channel quad 0..3 (wave id)
  const int p = blockIdx.x * 64 + lane; // 98*64 = 6272 = BP exactly
  const int o_base = blockIdx.y * 16;
  if (FUSE3 && t < 64) {
    int cb_l = t >> 4, k = t & 15;
    const float4 cf = *(const float4*)(c3cent + ((size_t)(blockIdx.y * 4 + cb_l)) * 64 + k * 4);
    c3f[cb_l][k][0] = cf.x; c3f[cb_l][k][1] = cf.y;
    c3f[cb_l][k][2] = cf.z; c3f[cb_l][k][3] = cf.w;
    double d0 = (double)cf.x, d1 = (double)cf.y, d2 = (double)cf.z, d3 = (double)cf.w;
    c3d[cb_l][k][0] = d0; c3d[cb_l][k][1] = d1;
    c3d[cb_l][k][2] = d2; c3d[cb_l][k][3] = d3;
    double s = 0.0; s += d0 * d0; s += d1 * d1; s += d2 * d2; s += d3 * d3;
    c3c2d[cb_l][k] = s;
    float s32 = 0.f; s32 += cf.x * cf.x; s32 += cf.y * cf.y;
    s32 += cf.z * cf.z; s32 += cf.w * cf.w;
    c3c2f[cb_l][k] = s32;
  }
  // staging ownership (coalesced source): thread t owns cb=(t>>6)+4j,
  // q_s = t&3, k = (t>>2)&15; 4 consecutive lanes = 64B contiguous of one row.
  const float* src = lut + ((size_t)(t >> 6) * 16 + ((t >> 2) & 15)) * NOUT
                         + o_base + (t & 3) * 4;
  const int kk = (t >> 2) & 15, qs = t & 3;
  const int sslot = (t >> 6) * 64 + qs * 16 + (kk ^ (2 * qs));
  const int q2 = q * 2;               // wave-uniform gather swizzle term
  double a0 = 0, a1 = 0, a2 = 0, a3 = 0;
  constexpr int NCHUNK = NCB / 16;
  for (int ch = 0; ch < NCHUNK; ch++) {
    __syncthreads();               // prior chunk's gathers done before overwrite
    uint32_t w0 = idxp[(size_t)(ch * 2) * BP + p];
    uint32_t w1 = idxp[(size_t)(ch * 2 + 1) * BP + p];
    {
      const float* g = src + (size_t)(ch * 256) * NOUT;
#pragma unroll
      for (int j = 0; j < 4; j++) {
        float4 v = *(const float4*)(g + (size_t)(64 * j) * NOUT);
        *(float4*)(s_lut + (sslot + 256 * j) * 4) = v;
      }
    }
    __syncthreads();               // chunk published
    const float* buf = s_lut + q * 64;
#pragma unroll
    for (int jq = 0; jq < 4; jq++) {   // cb quad (4jq .. 4jq+3)
      const int cbb = 4 * jq * 256;
      uint32_t w = (jq < 2) ? w0 : w1;
      int sh = (jq & 1) * 16;
      int i0 = (int)((w >> sh) & 15u);
      int i1 = (int)((w >> (sh + 4)) & 15u);
      int i2 = (int)((w >> (sh + 8)) & 15u);
      int i3 = (int)((w >> (sh + 12)) & 15u);
      const float4 va = *(const float4*)(buf + cbb       + (i0 ^ q2) * 4);
      const float4 vb = *(const float4*)(buf + cbb + 256 + (i1 ^ q2) * 4);
      const float4 vc = *(const float4*)(buf + cbb + 512 + (i2 ^ q2) * 4);
      const float4 vd = *(const float4*)(buf + cbb + 768 + (i3 ^ q2) * 4);
      float s0 = (va.x + vb.x) + (vc.x + vd.x);
      float s1 = (va.y + vb.y) + (vc.y + vd.y);
      float s2 = (va.z + vb.z) + (vc.z + vd.z);
      float s3 = (va.w + vb.w) + (vc.w + vd.w);
      a0 += (double)s0; a1 += (double)s1; a2 += (double)s2; a3 += (double)s3;
    }
  }
  const unsigned b = (unsigned)p / 196u;
  const unsigned pr = (unsigned)p - b * 196u;
  const int o = o_base + q * 4;
  const float4 sc = *(const float4*)(scale + o);
  const float4 bs = *(const float4*)(bias + o);
  double r0 = a0 * (double)sc.x + (double)bs.x;
  double r1 = a1 * (double)sc.y + (double)bs.y;
  double r2 = a2 * (double)sc.z + (double)bs.z;
  double r3 = a3 * (double)sc.w + (double)bs.w;
  if (RELU) {
    r0 = fmax(r0, 0.0); r1 = fmax(r1, 0.0);
    r2 = fmax(r2, 0.0); r3 = fmax(r3, 0.0);
  }
  if (FUSE3) {
    // layer-3 assignment for codebook cb3 = blockIdx.y*4 + q (this thread's 4 ch)
    const int cb_l = q;
    float x0 = (float)r0, x1 = (float)r1, x2 = (float)r2, x3 = (float)r3;
    float best = 1e30f, sec = 1e30f; int bi = 0;
#pragma unroll
    for (int k = 0; k < 16; k++) {
      const float4 c = *(const float4*)&c3f[cb_l][k][0];
      float dot = x0 * c.x;
      dot = fmaf(x1, c.y, dot);
      dot = fmaf(x2, c.z, dot);
      dot = fmaf(x3, c.w, dot);
      float dist = fmaf(-2.f, dot, c3c2f[cb_l][k]);
      if (dist < best) { sec = best; best = dist; bi = k; }
      else sec = fminf(sec, dist);
    }
    if (__any(sec - best < 1e-3f)) {
      double bb = 1e300; int bi64 = 0;
#pragma unroll
      for (int k = 0; k < 16; k++) {
        double dot = 0.0;
        dot = fma(r0, c3d[cb_l][k][0], dot);
        dot = fma(r1, c3d[cb_l][k][1], dot);
        dot = fma(r2, c3d[cb_l][k][2], dot);
        dot = fma(r3, c3d[cb_l][k][3], dot);
        double dist = c3c2d[cb_l][k] - 2.0 * dot;
        if (dist < bb) { bb = dist; bi64 = k; }   // strict <: first-min
      }
      bi = bi64;
    }
    // transposed layout: i3b[chunk16][p][16]  (chunk16 = cb3>>4, byte = cb3&15)
    i3b[((size_t)(blockIdx.y >> 2) * BP + p) * 16 + (blockIdx.y & 3) * 4 + q] =
        (uint8_t)bi;
  } else {
    OutT* op = out + ((size_t)b * NOUT + o) * PP + pr;
    op[0 * PP] = (OutT)r0; op[1 * PP] = (OutT)r1;
    op[2 * PP] = (OutT)r2; op[3 * PP] = (OutT)r3;
  }
}

// ---------------------------------------------------------------------------
// accum3 v3 (R11-verified): 256 positions per block (grid 25x64) -- each
// staged chunk serves TWO position-groups, halving LUT->LDS staging traffic.
// Tail block (x=24) covers p 6144..6271 in group A; group B fully guarded.
// Staging: 4 lanes x float4 per LUT row; ds_write_b64 at row*80 + c*8 ->
// conflict-free. Rows 40 halfs: gather quad (5*idx+h)%8 bijective -> 2-way
// = free. Index reads: lane-contiguous dwordx4 from transposed i3b.
// ---------------------------------------------------------------------------
__global__ __launch_bounds__(256) void accum3_f16(
    const float* __restrict__ lut, const uint8_t* __restrict__ i3b,
    const float* __restrict__ scale, const float* __restrict__ bias,
    const float* __restrict__ res, float* __restrict__ out) {
  __shared__ half_t s16[16 * 640];   // 20 KB
  const int t = threadIdx.x;
  const int lane = t & 63;
  const int wave = t >> 6;           // 0..3
  const int h = wave & 1;            // channel half (8 f16 ch)
  const int pg = wave >> 1;          // 0..1
  const int pA = blockIdx.x * 256 + pg * 64 + lane;   // always < BP
  const int pB = pA + 128;                            // may exceed BP (x=24)
  const bool okB = (pB < BP);
  const int pBc = okB ? pB : (BP - 1);                // clamped for loads
  const int o_base = blockIdx.y * 16;
  const int rs = t >> 2, cg = t & 3;
  const size_t cs = (size_t)16 * 16 * 1024;     // 16 cb per chunk (f32 elems)
  constexpr int NCHUNK = 4;
  float accA[8], accB[8];
#pragma unroll
  for (int i = 0; i < 8; i++) { accA[i] = 0.f; accB[i] = 0.f; }
  for (int ch = 0; ch < NCHUNK; ch++) {
    __syncthreads();
    const uint4 iwA = *(const uint4*)(i3b + ((size_t)ch * BP + pA) * 16);
    const uint4 iwB = *(const uint4*)(i3b + ((size_t)ch * BP + pBc) * 16);
    {
#pragma unroll
      for (int j = 0; j < 4; j++) {
        const int r = rs + 64 * j;
        const float4 v = *(const float4*)(lut + (size_t)ch * cs +
                                          (size_t)r * 1024 + o_base + cg * 4);
        half4v hv;
        hv[0] = (half_t)v.x; hv[1] = (half_t)v.y;
        hv[2] = (half_t)v.z; hv[3] = (half_t)v.w;
        *(half4v*)(s16 + (r >> 4) * 640 + (r & 15) * 40 + cg * 4) = hv;
      }
    }
    __syncthreads();
#pragma unroll
    for (int grp = 0; grp < 2; grp++) {   // 8 cb per f32 flush
      // ---- position group A ----
      {
        uint32_t wa = grp ? iwA.z : iwA.x;
        uint32_t wb = grp ? iwA.w : iwA.y;
        half2v p0 = 0, p1 = 0, p2 = 0, p3 = 0;
#pragma unroll
        for (int j = 0; j < 8; j++) {
          uint32_t w = (j < 4) ? wa : wb;
          int idx = (int)((w >> ((j & 3) * 8)) & 15u);
          int cb_l = grp * 8 + j;
          const half8v v = *(const half8v*)(s16 + cb_l * 640 + idx * 40 + h * 8);
          const half2v* vp = (const half2v*)&v;
          p0 += vp[0]; p1 += vp[1]; p2 += vp[2]; p3 += vp[3];
        }
        accA[0] += (float)p0[0]; accA[1] += (float)p0[1];
        accA[2] += (float)p1[0]; accA[3] += (float)p1[1];
        accA[4] += (float)p2[0]; accA[5] += (float)p2[1];
        accA[6] += (float)p3[0]; accA[7] += (float)p3[1];
      }
      // ---- position group B ----
      {
        uint32_t wa = grp ? iwB.z : iwB.x;
        uint32_t wb = grp ? iwB.w : iwB.y;
        half2v p0 = 0, p1 = 0, p2 = 0, p3 = 0;
#pragma unroll
        for (int j = 0; j < 8; j++) {
          uint32_t w = (j < 4) ? wa : wb;
          int idx = (int)((w >> ((j & 3) * 8)) & 15u);
          int cb_l = grp * 8 + j;
          const half8v v = *(const half8v*)(s16 + cb_l * 640 + idx * 40 + h * 8);
          const half2v* vp = (const half2v*)&v;
          p0 += vp[0]; p1 += vp[1]; p2 += vp[2]; p3 += vp[3];
        }
        accB[0] += (float)p0[0]; accB[1] += (float)p0[1];
        accB[2] += (float)p1[0]; accB[3] += (float)p1[1];
        accB[4] += (float)p2[0]; accB[5] += (float)p2[1];
        accB[6] += (float)p3[0]; accB[7] += (float)p3[1];
      }
    }
  }
  const int o = o_base + h * 8;
  {
    const unsigned b = (unsigned)pA / 196u;
    const unsigned pr = (unsigned)pA - b * 196u;
    const float* rp = res + ((size_t)b * 1024 + o) * PP + pr;
    float* op = out + ((size_t)b * 1024 + o) * PP + pr;
#pragma unroll
    for (int i = 0; i < 8; i++) {
      float v = accA[i] * scale[o + i] + bias[o + i] + rp[(size_t)i * PP];
      op[(size_t)i * PP] = fmaxf(v, 0.f);
    }
  }
  if (okB) {
    const unsigned b = (unsigned)pB / 196u;
    const unsigned pr = (unsigned)pB - b * 196u;
    const float* rp = res + ((size_t)b * 1024 + o) * PP + pr;
    float* op = out + ((size_t)b * 1024 + o) * PP + pr;
#pragma unroll
    for (int i = 0; i < 8; i++) {
      float v = accB[i] * scale[o + i] + bias[o + i] + rp[(size_t)i * PP];
      op[(size_t)i * PP] = fmaxf(v, 0.f);
    }
  }
}

// ---------------------------------------------------------------------------

extern "C" void kernel_launch(void* const* d_in, const int* in_sizes, int n_in,
                              void* d_out, int out_size, void* d_ws, size_t ws_size,
                              hipStream_t stream) {
  const float* x   = (const float*)d_in[0];   // [32,1024,14,14]
  const float* c1c = (const float*)d_in[1];
  const float* c1l = (const float*)d_in[2];
  const float* c1s = (const float*)d_in[3];
  const float* c1b = (const float*)d_in[4];
  const float* c2c = (const float*)d_in[5];
  const float* c2l = (const float*)d_in[6];
  const float* c2s = (const float*)d_in[7];
  const float* c2b = (const float*)d_in[8];
  const float* c3c = (const float*)d_in[9];
  const float* c3l = (const float*)d_in[10];  // [64,16,1024]
  const float* c3s = (const float*)d_in[11];
  const float* c3b = (const float*)d_in[12];

  const size_t sz_i1  = (size_t)32 * BP * 4;      // 802,816 B
  const size_t sz_i2  = (size_t)32 * BP * 4;
  const size_t sz_i3b = (size_t)BP * 64;          // 401,408 B (byte indices)
  const size_t sz_o32 = (size_t)BP * 256 * 4;     // 6.42 MB (f32 layer-1 out)

  char* w = (char*)d_ws;
  uint32_t* i1 = (uint32_t*)w; w += sz_i1;
  uint32_t* i2 = (uint32_t*)w; w += sz_i2;
  uint8_t* i3b = (uint8_t*)w;  w += sz_i3b;
  float* out1;
  if (ws_size >= (size_t)(w - (char*)d_ws) + sz_o32) {
    out1 = (float*)w;
  } else {
    // d_out (25.69 MB f32) holds out1 (6.42 MB f32) in its first quarter;
    // accum3 (final) reads only i3b/x/c3l, then overwrites all of d_out.
    out1 = (float*)d_out;
  }

  const dim3 blkA(256), blkC(256);
  // layer 1: 1x1, 256 codebooks (dsub=4) over 1024 input channels
  assign_1x1<float><<<dim3(25, 32), blkA, 0, stream>>>(x, c1c, i1, 1024);
  accum_f64<256, 256, true, false, float><<<dim3(98, 16), blkC, 0, stream>>>(
      c1l, i1, c1s, c1b, nullptr, nullptr, out1);
  // layer 2: 3x3, 256 codebooks (dsub=9); epilogue fuses the layer-3 assign
  assign_3x3<<<dim3(25, 32), blkA, 0, stream>>>(out1, c2c, i2);
  accum_f64<256, 256, true, true, float><<<dim3(98, 16), blkC, 0, stream>>>(
      c2l, i2, c2s, c2b, c3c, i3b, nullptr);
  // layer 3: 64 codebooks over 256 channels; fused residual + relu
  accum3_f16<<<dim3(25, 64), blkC, 0, stream>>>(
      c3l, i3b, c3s, c3b, x, (float*)d_out);
}